// Round 2
// baseline (2636.102 us; speedup 1.0000x reference)
//
#include <hip/hip_runtime.h>
#include <math.h>

#define N_ROWS 16384
#define DIM 512
#define NE 8192

// d_out layout (floats), reference return order:
// loss[1], z_q_st[32*512*512], perplexity[1], min_encodings[16384*8192], idx[16384]
#define LOSS_OFF 0UL
#define ZQ_OFF 1UL
#define PERP_OFF 8388609UL
#define ME_OFF 8388610UL
#define IDX_OFF 142606338UL

// ---------------- zero-fill of min_encodings + scratch init ----------------
__global__ void zero_fill_kernel(float* __restrict__ out, int* __restrict__ hist) {
    // min_encodings region starts at ME_OFF (16B-misaligned by 8 bytes):
    // 2 scalar head, 33554431 float4, 2 scalar tail.
    const size_t FQ = 33554431UL;
    float4* base = reinterpret_cast<float4*>(out + ME_OFF + 2);
    const float4 z4 = make_float4(0.f, 0.f, 0.f, 0.f);
    const size_t stride = (size_t)gridDim.x * blockDim.x;
    for (size_t i = (size_t)blockIdx.x * blockDim.x + threadIdx.x; i < FQ; i += stride)
        base[i] = z4;
    const size_t gtid = (size_t)blockIdx.x * blockDim.x + threadIdx.x;
    if (gtid < NE) hist[gtid] = 0;
    if (gtid == NE) {
        out[LOSS_OFF] = 0.f;
        out[ME_OFF] = 0.f;
        out[ME_OFF + 1] = 0.f;
        out[ME_OFF + 2 + 4 * FQ] = 0.f;
        out[ME_OFF + 2 + 4 * FQ + 1] = 0.f;
    }
}

// ---------------- ||z||^2 per row ----------------
// Any fp32 summation order works: the quantized-argmin structure is invariant
// to k-ulp shifts of znorm within a binade (see session notes).
__global__ void znorm_kernel(const float* __restrict__ z, float* __restrict__ znorm) {
    const int wave = (blockIdx.x * blockDim.x + threadIdx.x) >> 6;
    const int lane = threadIdx.x & 63;
    if (wave >= N_ROWS) return;
    const float* row = z + (size_t)wave * DIM;
    float s = 0.f;
#pragma unroll
    for (int j = 0; j < 8; j++) {
        const float v = row[lane + j * 64];
        s = fmaf(v, v, s);
    }
#pragma unroll
    for (int off = 32; off; off >>= 1) s += __shfl_down(s, off, 64);
    if (lane == 0) znorm[wave] = s;
}

// ---------------- fused GEMM + quantized argmin ----------------
// Reference semantics: d = fl(znorm_row - 2*M) in fp32 (the ||e||^2 term is
// provably absorbed: ||e||^2 <= 7.6e-6 < half-ulp(znorm~512) = 1.5e-5).
// Argmin with numpy first-occurrence tie-break (strict <, ascending index).
#define MT 64
#define ET 128
#define KT 16

__launch_bounds__(256, 2)
__global__ void argmin_kernel(const float* __restrict__ z, const float* __restrict__ emb,
                              const float* __restrict__ znorm,
                              float* __restrict__ cand_val, int* __restrict__ cand_idx) {
    __shared__ float As[KT][68];    // [k][row], pad 64->68
    __shared__ float Bs[KT][132];   // [k][code], pad 128->132
    __shared__ float rv[MT][17];
    __shared__ int   ri[MT][17];

    const int tid = threadIdx.x;
    const int tx = tid & 15;
    const int ty = tid >> 4;
    const int m0 = blockIdx.x * MT;
    const int ebase = blockIdx.y * (NE / 2);

    float zn[4];
#pragma unroll
    for (int r = 0; r < 4; r++) zn[r] = znorm[m0 + ty * 4 + r];

    float bestv[4];
    int besti[4];
#pragma unroll
    for (int r = 0; r < 4; r++) { bestv[r] = INFINITY; besti[r] = 0; }

    const int k4 = tid & 3;      // float4 column within K-chunk
    const int ldrow = tid >> 2;  // 0..63

    for (int et = 0; et < (NE / 2) / ET; ++et) {
        const int e0 = ebase + et * ET;

        float acc[4][8];
#pragma unroll
        for (int r = 0; r < 4; r++)
#pragma unroll
            for (int c = 0; c < 8; c++) acc[r][c] = 0.f;

        for (int kt = 0; kt < DIM / KT; ++kt) {
            // stage A tile (64 x 16), transposed into LDS
            {
                const float4 v = *reinterpret_cast<const float4*>(
                    &z[(size_t)(m0 + ldrow) * DIM + kt * KT + k4 * 4]);
                As[k4 * 4 + 0][ldrow] = v.x;
                As[k4 * 4 + 1][ldrow] = v.y;
                As[k4 * 4 + 2][ldrow] = v.z;
                As[k4 * 4 + 3][ldrow] = v.w;
            }
            // stage B tile (128 x 16), transposed
#pragma unroll
            for (int i = 0; i < 2; i++) {
                const int code = ldrow + i * 64;
                const float4 v = *reinterpret_cast<const float4*>(
                    &emb[(size_t)(e0 + code) * DIM + kt * KT + k4 * 4]);
                Bs[k4 * 4 + 0][code] = v.x;
                Bs[k4 * 4 + 1][code] = v.y;
                Bs[k4 * 4 + 2][code] = v.z;
                Bs[k4 * 4 + 3][code] = v.w;
            }
            __syncthreads();
#pragma unroll
            for (int kk = 0; kk < KT; kk++) {
                const float4 a  = *reinterpret_cast<const float4*>(&As[kk][ty * 4]);
                const float4 b0 = *reinterpret_cast<const float4*>(&Bs[kk][tx * 4]);
                const float4 b1 = *reinterpret_cast<const float4*>(&Bs[kk][64 + tx * 4]);
                const float av[4] = {a.x, a.y, a.z, a.w};
                const float bv[8] = {b0.x, b0.y, b0.z, b0.w, b1.x, b1.y, b1.z, b1.w};
#pragma unroll
                for (int r = 0; r < 4; r++)
#pragma unroll
                    for (int c = 0; c < 8; c++)
                        acc[r][c] = fmaf(av[r], bv[c], acc[r][c]);
            }
            __syncthreads();
        }
        // quantized distance t = fl(znorm - 2*z.e); running first-min argmin
        // (codes visited in ascending index order, strict <)
#pragma unroll
        for (int c = 0; c < 8; c++) {
            const int lc = (c < 4) ? (tx * 4 + c) : (64 + tx * 4 + (c - 4));
            const int gidx = e0 + lc;
#pragma unroll
            for (int r = 0; r < 4; r++) {
                const float t = fmaf(-2.f, acc[r][c], zn[r]);
                if (t < bestv[r]) { bestv[r] = t; besti[r] = gidx; }
            }
        }
    }

    // cross-thread (tx) reduction per row, lowest index wins ties
#pragma unroll
    for (int r = 0; r < 4; r++) {
        rv[ty * 4 + r][tx] = bestv[r];
        ri[ty * 4 + r][tx] = besti[r];
    }
    __syncthreads();
    if (tid < MT) {
        float bv = rv[tid][0];
        int bi = ri[tid][0];
#pragma unroll
        for (int t = 1; t < 16; t++) {
            const float v = rv[tid][t];
            const int i = ri[tid][t];
            if (v < bv || (v == bv && i < bi)) { bv = v; bi = i; }
        }
        cand_val[(size_t)blockIdx.y * N_ROWS + m0 + tid] = bv;
        cand_idx[(size_t)blockIdx.y * N_ROWS + m0 + tid] = bi;
    }
}

// ---------------- finalize: pick idx, gather z_q, loss, one-hot, idx out ----
__global__ void finalize_kernel(const float* __restrict__ z, const float* __restrict__ emb,
                                const float* __restrict__ cand_val, const int* __restrict__ cand_idx,
                                float* __restrict__ out, int* __restrict__ hist) {
    __shared__ float sdata[256];
    const int n = blockIdx.x;
    const float v0 = cand_val[n];
    const float v1 = cand_val[N_ROWS + n];
    const int i0 = cand_idx[n];
    const int i1 = cand_idx[N_ROWS + n];
    const int idx = (v1 < v0) ? i1 : i0;  // tie -> lower half -> lower index (np first-min)
    const float* e = emb + (size_t)idx * DIM;
    const float* zr = z + (size_t)n * DIM;
    const int tid = threadIdx.x;
    float ls = 0.f;
#pragma unroll
    for (int j = 0; j < 2; j++) {
        const int k = tid + j * 256;
        const float zq = e[k];
        const float zv = zr[k];
        const float d = zq - zv;             // match reference rounding:
        out[ZQ_OFF + (size_t)n * DIM + k] = zv + d;  // z + (z_q - z)
        ls += d * d;
    }
    sdata[tid] = ls;
    __syncthreads();
    for (int s = 128; s; s >>= 1) {
        if (tid < s) sdata[tid] += sdata[tid + s];
        __syncthreads();
    }
    if (tid == 0) {
        atomicAdd(out + LOSS_OFF, sdata[0] * (1.25f / 8388608.f));
        atomicAdd(hist + idx, 1);
        out[ME_OFF + (size_t)n * NE + idx] = 1.0f;
        out[IDX_OFF + n] = (float)idx;
    }
}

// ---------------- perplexity from histogram ----------------
__global__ void perp_kernel(const int* __restrict__ hist, float* __restrict__ out) {
    __shared__ float sdata[256];
    const int tid = threadIdx.x;
    float s = 0.f;
    for (int b = tid; b < NE; b += 256) {
        const float p = (float)hist[b] * (1.0f / 16384.f);
        s += p * logf(p + 1e-10f);
    }
    sdata[tid] = s;
    __syncthreads();
    for (int st = 128; st; st >>= 1) {
        if (tid < st) sdata[tid] += sdata[tid + st];
        __syncthreads();
    }
    if (tid == 0) out[PERP_OFF] = expf(-sdata[0]);
}

extern "C" void kernel_launch(void* const* d_in, const int* in_sizes, int n_in,
                              void* d_out, int out_size, void* d_ws, size_t ws_size,
                              hipStream_t stream) {
    const float* z = (const float*)d_in[0];    // [32,512,512]
    const float* emb = (const float*)d_in[1];  // [8192,512]
    float* out = (float*)d_out;
    float* ws = (float*)d_ws;

    float* znorm = ws;                                   // 16384 f32
    float* cand_val = ws + N_ROWS;                       // 2*16384 f32
    int* cand_idx = (int*)(ws + 3 * N_ROWS);             // 2*16384 i32
    int* hist = (int*)(ws + 5 * N_ROWS);                 // 8192 i32

    hipLaunchKernelGGL(zero_fill_kernel, dim3(2048), dim3(256), 0, stream, out, hist);
    hipLaunchKernelGGL(znorm_kernel, dim3(N_ROWS * 64 / 256), dim3(256), 0, stream, z, znorm);
    hipLaunchKernelGGL(argmin_kernel, dim3(N_ROWS / MT, 2), dim3(256), 0, stream,
                       z, emb, znorm, cand_val, cand_idx);
    hipLaunchKernelGGL(finalize_kernel, dim3(N_ROWS), dim3(256), 0, stream,
                       z, emb, cand_val, cand_idx, out, hist);
    hipLaunchKernelGGL(perp_kernel, dim3(1), dim3(256), 0, stream, hist, out);
}

// Round 5
// 1646.809 us; speedup vs baseline: 1.6007x; 1.6007x over previous
//
#include <hip/hip_runtime.h>
#include <math.h>

#define N_ROWS 16384
#define DIM 512
#define NE 8192

// d_out layout (floats), reference return order:
// loss[1], z_q_st[32*512*512], perplexity[1], min_encodings[16384*8192], idx[16384]
#define LOSS_OFF 0UL
#define ZQ_OFF 1UL
#define PERP_OFF 8388609UL
#define ME_OFF 8388610UL
#define IDX_OFF 142606338UL

typedef __attribute__((ext_vector_type(8))) short bf16x8;
typedef __attribute__((ext_vector_type(4))) float f32x4;

// 3-way bf16 split (RNE): f = h + m + l + eps, |eps| <~ 2^-24 |f|
__device__ __forceinline__ void bsplit3(float f, ushort& h, ushort& m, ushort& l) {
    uint u = __float_as_uint(f);
    uint hb = (u + 0x7FFFu + ((u >> 16) & 1u)) >> 16;
    float fh = __uint_as_float(hb << 16);
    float r1 = f - fh;                       // exact (Sterbenz)
    uint u1 = __float_as_uint(r1);
    uint mb = (u1 + 0x7FFFu + ((u1 >> 16) & 1u)) >> 16;
    float fm = __uint_as_float(mb << 16);
    float r2 = r1 - fm;                      // exact
    uint u2 = __float_as_uint(r2);
    uint lb = (u2 + 0x7FFFu + ((u2 >> 16) & 1u)) >> 16;
    h = (ushort)hb; m = (ushort)mb; l = (ushort)lb;
}

// ---------------- zero-fill of min_encodings + scratch init ----------------
__global__ void zero_fill_kernel(float* __restrict__ out, int* __restrict__ hist) {
    const size_t FQ = 33554431UL;
    f32x4* base = reinterpret_cast<f32x4*>(out + ME_OFF + 2);
    const f32x4 z4 = (f32x4){0.f, 0.f, 0.f, 0.f};
    const size_t stride = (size_t)gridDim.x * blockDim.x;
    for (size_t i = (size_t)blockIdx.x * blockDim.x + threadIdx.x; i < FQ; i += stride)
        __builtin_nontemporal_store(z4, &base[i]);
    const size_t gtid = (size_t)blockIdx.x * blockDim.x + threadIdx.x;
    if (gtid < NE) hist[gtid] = 0;
    if (gtid == NE) {
        out[LOSS_OFF] = 0.f;
        out[ME_OFF] = 0.f;
        out[ME_OFF + 1] = 0.f;
        out[ME_OFF + 2 + 4 * FQ] = 0.f;
        out[ME_OFF + 2 + 4 * FQ + 1] = 0.f;
    }
}

// ---------------- ||z||^2 per row ----------------
__global__ void znorm_kernel(const float* __restrict__ z, float* __restrict__ znorm) {
    const int wave = (blockIdx.x * blockDim.x + threadIdx.x) >> 6;
    const int lane = threadIdx.x & 63;
    if (wave >= N_ROWS) return;
    const float* row = z + (size_t)wave * DIM;
    float s = 0.f;
#pragma unroll
    for (int j = 0; j < 8; j++) {
        const float v = row[lane + j * 64];
        s = fmaf(v, v, s);
    }
#pragma unroll
    for (int off = 32; off; off >>= 1) s += __shfl_down(s, off, 64);
    if (lane == 0) znorm[wave] = s;
}

// ---------------- emb 3-way bf16 split into ws ----------------
__global__ void emb_split_kernel(const float* __restrict__ emb, ushort* __restrict__ eh,
                                 ushort* __restrict__ em, ushort* __restrict__ el) {
    const size_t g = (size_t)blockIdx.x * blockDim.x + threadIdx.x;  // < 1048576 float4s
    const float4 v = reinterpret_cast<const float4*>(emb)[g];
    ushort h[4], m[4], l[4];
    bsplit3(v.x, h[0], m[0], l[0]);
    bsplit3(v.y, h[1], m[1], l[1]);
    bsplit3(v.z, h[2], m[2], l[2]);
    bsplit3(v.w, h[3], m[3], l[3]);
    reinterpret_cast<ushort4*>(eh)[g] = make_ushort4(h[0], h[1], h[2], h[3]);
    reinterpret_cast<ushort4*>(em)[g] = make_ushort4(m[0], m[1], m[2], m[3]);
    reinterpret_cast<ushort4*>(el)[g] = make_ushort4(l[0], l[1], l[2], l[3]);
}

// ---------------- MFMA fused GEMM + quantized argmin ----------------
// Block: 128 rows x 2048 codes (quarter q), 4 waves in 2x2 of 64x64 sub-tiles.
// Waves (0,1) share rows 0..63 (halves wn=0/64); (2,3) share rows 64..127.
// Their per-row winners are merged in LDS before the single cand write
// (R4 bug: both halves raced on the same cand slot).
#define MBLK 128
#define NBLK 128
#define QCODES 2048

__launch_bounds__(256, 2)
__global__ void argmin_mfma_kernel(const float* __restrict__ z,
                                   const ushort* __restrict__ eh,
                                   const ushort* __restrict__ em,
                                   const ushort* __restrict__ el,
                                   const float* __restrict__ znorm,
                                   float* __restrict__ cand_val, int* __restrict__ cand_idx) {
    __shared__ __align__(16) ushort A_lds[3][8][64][8];
    __shared__ __align__(16) ushort B_lds[3][8][64][8];
    __shared__ float mvals[2][2][64];
    __shared__ int   midxs[2][2][64];

    const int tid = threadIdx.x;
    const int w = tid >> 6;
    const int lane = tid & 63;
    const int lane16 = lane & 15;
    const int lq = lane >> 4;
    const int m0 = blockIdx.x * MBLK;
    const int q = blockIdx.y;
    const int wm = (w >> 1) * 64;
    const int wn = (w & 1) * 64;

    const ushort* esp[3] = {eh, em, el};

    float zn[16];
#pragma unroll
    for (int im = 0; im < 4; im++)
#pragma unroll
        for (int r = 0; r < 4; r++)
            zn[im * 4 + r] = znorm[m0 + wm + im * 16 + lq * 4 + r];

    float bestv[16];
    int besti[16];
#pragma unroll
    for (int s = 0; s < 16; s++) { bestv[s] = INFINITY; besti[s] = 0; }

    for (int nt = 0; nt < QCODES / NBLK; nt++) {
        const int n0 = q * QCODES + nt * NBLK;
        f32x4 acc[4][4];
#pragma unroll
        for (int im = 0; im < 4; im++)
#pragma unroll
            for (int in = 0; in < 4; in++)
                acc[im][in] = (f32x4){0.f, 0.f, 0.f, 0.f};

        for (int kc = 0; kc < DIM / 32; kc++) {
            const int k0 = kc * 32;
            // B staging: async global->LDS, wave w handles 6 (term,group) pairs
#pragma unroll
            for (int c = 0; c < 6; c++) {
                const int pg = w + c * 4;
                const int t = pg >> 3, g = pg & 7;
                const ushort* src = esp[t] +
                    ((size_t)(n0 + g * 16 + lane16) * DIM + k0 + lq * 8);
                __builtin_amdgcn_global_load_lds(
                    (const __attribute__((address_space(1))) void*)src,
                    (__attribute__((address_space(3))) void*)&B_lds[t][g][0][0],
                    16, 0, 0);
            }
            // A staging: load fp32 z tile (128x32), split to 3 bf16 terms
#pragma unroll
            for (int p = 0; p < 4; p++) {
                const int li = p * 256 + tid;
                const int m = li >> 3, k4 = li & 7;
                const float4 v = *reinterpret_cast<const float4*>(
                    &z[(size_t)(m0 + m) * DIM + k0 + k4 * 4]);
                ushort h[4], mm[4], ll[4];
                bsplit3(v.x, h[0], mm[0], ll[0]);
                bsplit3(v.y, h[1], mm[1], ll[1]);
                bsplit3(v.z, h[2], mm[2], ll[2]);
                bsplit3(v.w, h[3], mm[3], ll[3]);
                const int g = m >> 4, gr = (k4 >> 1) * 16 + (m & 15), j0 = (k4 & 1) * 4;
                *reinterpret_cast<ushort4*>(&A_lds[0][g][gr][j0]) = make_ushort4(h[0], h[1], h[2], h[3]);
                *reinterpret_cast<ushort4*>(&A_lds[1][g][gr][j0]) = make_ushort4(mm[0], mm[1], mm[2], mm[3]);
                *reinterpret_cast<ushort4*>(&A_lds[2][g][gr][j0]) = make_ushort4(ll[0], ll[1], ll[2], ll[3]);
            }
            __syncthreads();
            bf16x8 bfr[3][4];
#pragma unroll
            for (int t = 0; t < 3; t++)
#pragma unroll
                for (int in = 0; in < 4; in++)
                    bfr[t][in] = *reinterpret_cast<const bf16x8*>(&B_lds[t][(wn >> 4) + in][lane][0]);
#pragma unroll
            for (int t = 0; t < 3; t++) {
                bf16x8 afr[4];
#pragma unroll
                for (int im = 0; im < 4; im++)
                    afr[im] = *reinterpret_cast<const bf16x8*>(&A_lds[t][(wm >> 4) + im][lane][0]);
                // term pairs: (h,*): hh,hm,hl ; (m,*): mh,mm ; (l,*): lh  -> 6 total
#pragma unroll
                for (int u = 0; u < 3 - t; u++)
#pragma unroll
                    for (int im = 0; im < 4; im++)
#pragma unroll
                        for (int in = 0; in < 4; in++)
                            acc[im][in] = __builtin_amdgcn_mfma_f32_16x16x32_bf16(
                                afr[im], bfr[u][in], acc[im][in], 0, 0, 0);
            }
            __syncthreads();
        }
        // epilogue: t = fl(zn - 2*dot), running first-min (ascending code order)
#pragma unroll
        for (int im = 0; im < 4; im++)
#pragma unroll
            for (int r = 0; r < 4; r++) {
                const int s = im * 4 + r;
#pragma unroll
                for (int in = 0; in < 4; in++) {
                    const float dv = fmaf(-2.f, acc[im][in][r], zn[s]);
                    const int code = n0 + wn + in * 16 + lane16;
                    if (dv < bestv[s]) { bestv[s] = dv; besti[s] = code; }
                }
            }
    }
    // cross-lane reduce over the 16 lanes (same lq) sharing each row
#pragma unroll
    for (int s = 0; s < 16; s++) {
        float bv = bestv[s];
        int bi = besti[s];
#pragma unroll
        for (int off = 1; off < 16; off <<= 1) {
            const float v2 = __shfl_xor(bv, off, 64);
            const int i2 = __shfl_xor(bi, off, 64);
            if (v2 < bv || (v2 == bv && i2 < bi)) { bv = v2; bi = i2; }
        }
        if (lane16 == 0) {
            const int im = s >> 2, r = s & 3;
            const int rloc = im * 16 + lq * 4 + r;  // 0..63 within wave's row block
            mvals[w >> 1][w & 1][rloc] = bv;
            midxs[w >> 1][w & 1][rloc] = bi;
        }
    }
    __syncthreads();
    // merge the two code-halves per wave-pair; lower index wins ties
    if (tid < 128) {
        const int wp = tid >> 6, rl = tid & 63;
        const float v0 = mvals[wp][0][rl], v1 = mvals[wp][1][rl];
        const int i0 = midxs[wp][0][rl], i1 = midxs[wp][1][rl];
        float bv; int bi;
        if (v1 < v0 || (v1 == v0 && i1 < i0)) { bv = v1; bi = i1; }
        else { bv = v0; bi = i0; }
        const int row = m0 + wp * 64 + rl;
        cand_val[(size_t)q * N_ROWS + row] = bv;
        cand_idx[(size_t)q * N_ROWS + row] = bi;
    }
}

// ---------------- fallback fp32 vector argmin (R2, proven) ----------------
#define MT 64
#define ET 128
#define KT 16
__launch_bounds__(256, 2)
__global__ void argmin_vec_kernel(const float* __restrict__ z, const float* __restrict__ emb,
                                  const float* __restrict__ znorm,
                                  float* __restrict__ cand_val, int* __restrict__ cand_idx) {
    __shared__ float As[KT][68];
    __shared__ float Bs[KT][132];
    __shared__ float rv[MT][17];
    __shared__ int ri[MT][17];
    const int tid = threadIdx.x;
    const int tx = tid & 15;
    const int ty = tid >> 4;
    const int m0 = blockIdx.x * MT;
    const int ebase = blockIdx.y * (NE / 2);
    float zn[4];
#pragma unroll
    for (int r = 0; r < 4; r++) zn[r] = znorm[m0 + ty * 4 + r];
    float bestv[4]; int besti[4];
#pragma unroll
    for (int r = 0; r < 4; r++) { bestv[r] = INFINITY; besti[r] = 0; }
    const int k4 = tid & 3;
    const int ldrow = tid >> 2;
    for (int et = 0; et < (NE / 2) / ET; ++et) {
        const int e0 = ebase + et * ET;
        float acc[4][8];
#pragma unroll
        for (int r = 0; r < 4; r++)
#pragma unroll
            for (int c = 0; c < 8; c++) acc[r][c] = 0.f;
        for (int kt = 0; kt < DIM / KT; ++kt) {
            {
                const float4 v = *reinterpret_cast<const float4*>(
                    &z[(size_t)(m0 + ldrow) * DIM + kt * KT + k4 * 4]);
                As[k4 * 4 + 0][ldrow] = v.x; As[k4 * 4 + 1][ldrow] = v.y;
                As[k4 * 4 + 2][ldrow] = v.z; As[k4 * 4 + 3][ldrow] = v.w;
            }
#pragma unroll
            for (int i = 0; i < 2; i++) {
                const int code = ldrow + i * 64;
                const float4 v = *reinterpret_cast<const float4*>(
                    &emb[(size_t)(e0 + code) * DIM + kt * KT + k4 * 4]);
                Bs[k4 * 4 + 0][code] = v.x; Bs[k4 * 4 + 1][code] = v.y;
                Bs[k4 * 4 + 2][code] = v.z; Bs[k4 * 4 + 3][code] = v.w;
            }
            __syncthreads();
#pragma unroll
            for (int kk = 0; kk < KT; kk++) {
                const float4 a = *reinterpret_cast<const float4*>(&As[kk][ty * 4]);
                const float4 b0 = *reinterpret_cast<const float4*>(&Bs[kk][tx * 4]);
                const float4 b1 = *reinterpret_cast<const float4*>(&Bs[kk][64 + tx * 4]);
                const float av[4] = {a.x, a.y, a.z, a.w};
                const float bv[8] = {b0.x, b0.y, b0.z, b0.w, b1.x, b1.y, b1.z, b1.w};
#pragma unroll
                for (int r = 0; r < 4; r++)
#pragma unroll
                    for (int c = 0; c < 8; c++)
                        acc[r][c] = fmaf(av[r], bv[c], acc[r][c]);
            }
            __syncthreads();
        }
#pragma unroll
        for (int c = 0; c < 8; c++) {
            const int lc = (c < 4) ? (tx * 4 + c) : (64 + tx * 4 + (c - 4));
            const int gidx = e0 + lc;
#pragma unroll
            for (int r = 0; r < 4; r++) {
                const float t = fmaf(-2.f, acc[r][c], zn[r]);
                if (t < bestv[r]) { bestv[r] = t; besti[r] = gidx; }
            }
        }
    }
#pragma unroll
    for (int r = 0; r < 4; r++) { rv[ty * 4 + r][tx] = bestv[r]; ri[ty * 4 + r][tx] = besti[r]; }
    __syncthreads();
    if (tid < MT) {
        float bv = rv[tid][0]; int bi = ri[tid][0];
#pragma unroll
        for (int t = 1; t < 16; t++) {
            const float v = rv[tid][t]; const int i = ri[tid][t];
            if (v < bv || (v == bv && i < bi)) { bv = v; bi = i; }
        }
        cand_val[(size_t)blockIdx.y * N_ROWS + m0 + tid] = bv;
        cand_idx[(size_t)blockIdx.y * N_ROWS + m0 + tid] = bi;
    }
}

// ---------------- finalize: pick idx over nq candidates, gather, loss ----
__global__ void finalize_kernel(const float* __restrict__ z, const float* __restrict__ emb,
                                const float* __restrict__ cand_val, const int* __restrict__ cand_idx,
                                int nq, float* __restrict__ out, int* __restrict__ hist) {
    __shared__ float sdata[256];
    const int n = blockIdx.x;
    float v = cand_val[n];
    int idx = cand_idx[n];
    for (int qq = 1; qq < nq; qq++) {
        const float vq = cand_val[(size_t)qq * N_ROWS + n];
        const int iq = cand_idx[(size_t)qq * N_ROWS + n];
        if (vq < v || (vq == v && iq < idx)) { v = vq; idx = iq; }
    }
    const float* e = emb + (size_t)idx * DIM;
    const float* zr = z + (size_t)n * DIM;
    const int tid = threadIdx.x;
    float ls = 0.f;
#pragma unroll
    for (int j = 0; j < 2; j++) {
        const int k = tid + j * 256;
        const float zq = e[k];
        const float zv = zr[k];
        const float d = zq - zv;
        out[ZQ_OFF + (size_t)n * DIM + k] = zv + d;  // match ref rounding: z + (z_q - z)
        ls += d * d;
    }
    sdata[tid] = ls;
    __syncthreads();
    for (int s = 128; s; s >>= 1) {
        if (tid < s) sdata[tid] += sdata[tid + s];
        __syncthreads();
    }
    if (tid == 0) {
        atomicAdd(out + LOSS_OFF, sdata[0] * (1.25f / 8388608.f));
        atomicAdd(hist + idx, 1);
        out[ME_OFF + (size_t)n * NE + idx] = 1.0f;
        out[IDX_OFF + n] = (float)idx;
    }
}

// ---------------- perplexity from histogram ----------------
__global__ void perp_kernel(const int* __restrict__ hist, float* __restrict__ out) {
    __shared__ float sdata[256];
    const int tid = threadIdx.x;
    float s = 0.f;
    for (int b = tid; b < NE; b += 256) {
        const float p = (float)hist[b] * (1.0f / 16384.f);
        s += p * logf(p + 1e-10f);
    }
    sdata[tid] = s;
    __syncthreads();
    for (int st = 128; st; st >>= 1) {
        if (tid < st) sdata[tid] += sdata[tid + st];
        __syncthreads();
    }
    if (tid == 0) out[PERP_OFF] = expf(-sdata[0]);
}

extern "C" void kernel_launch(void* const* d_in, const int* in_sizes, int n_in,
                              void* d_out, int out_size, void* d_ws, size_t ws_size,
                              hipStream_t stream) {
    const float* z = (const float*)d_in[0];    // [32,512,512]
    const float* emb = (const float*)d_in[1];  // [8192,512]
    float* out = (float*)d_out;
    unsigned char* w = (unsigned char*)d_ws;

    const size_t ESP = 8388608UL;  // one emb split term: 8192*512*2 bytes
    const size_t NEED = 3 * ESP + 65536 + 524288 + 32768;

    if (ws_size >= NEED) {
        ushort* eh = (ushort*)w;
        ushort* em = (ushort*)(w + ESP);
        ushort* el = (ushort*)(w + 2 * ESP);
        float* znorm = (float*)(w + 3 * ESP);
        float* cand_val = (float*)(w + 3 * ESP + 65536);
        int* cand_idx = (int*)(w + 3 * ESP + 65536 + 262144);
        int* hist = (int*)(w + 3 * ESP + 65536 + 524288);

        hipLaunchKernelGGL(zero_fill_kernel, dim3(4096), dim3(256), 0, stream, out, hist);
        hipLaunchKernelGGL(emb_split_kernel, dim3(4096), dim3(256), 0, stream, emb, eh, em, el);
        hipLaunchKernelGGL(znorm_kernel, dim3(4096), dim3(256), 0, stream, z, znorm);
        hipLaunchKernelGGL(argmin_mfma_kernel, dim3(N_ROWS / MBLK, 4), dim3(256), 0, stream,
                           z, eh, em, el, znorm, cand_val, cand_idx);
        hipLaunchKernelGGL(finalize_kernel, dim3(N_ROWS), dim3(256), 0, stream,
                           z, emb, cand_val, cand_idx, 4, out, hist);
        hipLaunchKernelGGL(perp_kernel, dim3(1), dim3(256), 0, stream, hist, out);
    } else {
        float* znorm = (float*)w;                     // 16384 f32
        float* cand_val = (float*)(w + 65536);        // 2*16384 f32
        int* cand_idx = (int*)(w + 65536 + 131072);   // 2*16384 i32
        int* hist = (int*)(w + 65536 + 262144);       // 8192 i32

        hipLaunchKernelGGL(zero_fill_kernel, dim3(4096), dim3(256), 0, stream, out, hist);
        hipLaunchKernelGGL(znorm_kernel, dim3(4096), dim3(256), 0, stream, z, znorm);
        hipLaunchKernelGGL(argmin_vec_kernel, dim3(N_ROWS / MT, 2), dim3(256), 0, stream,
                           z, emb, znorm, cand_val, cand_idx);
        hipLaunchKernelGGL(finalize_kernel, dim3(N_ROWS), dim3(256), 0, stream,
                           z, emb, cand_val, cand_idx, 2, out, hist);
        hipLaunchKernelGGL(perp_kernel, dim3(1), dim3(256), 0, stream, hist, out);
    }
}

// Round 7
// 1244.706 us; speedup vs baseline: 2.1179x; 1.3231x over previous
//
#include <hip/hip_runtime.h>
#include <math.h>

#define N_ROWS 16384
#define DIM 512
#define NE 8192

// d_out layout (floats), reference return order:
// loss[1], z_q_st[32*512*512], perplexity[1], min_encodings[16384*8192], idx[16384]
#define LOSS_OFF 0UL
#define ZQ_OFF 1UL
#define PERP_OFF 8388609UL
#define ME_OFF 8388610UL
#define IDX_OFF 142606338UL

typedef __attribute__((ext_vector_type(8))) short bf16x8;
typedef __attribute__((ext_vector_type(8))) unsigned short u16x8;
typedef __attribute__((ext_vector_type(4))) float f32x4;

// 3-way bf16 split (RNE): f = h + m + l + eps, |eps| <~ 2^-24 |f| per element
__device__ __forceinline__ void bsplit3(float f, ushort& h, ushort& m, ushort& l) {
    uint u = __float_as_uint(f);
    uint hb = (u + 0x7FFFu + ((u >> 16) & 1u)) >> 16;
    float fh = __uint_as_float(hb << 16);
    float r1 = f - fh;                       // exact (Sterbenz)
    uint u1 = __float_as_uint(r1);
    uint mb = (u1 + 0x7FFFu + ((u1 >> 16) & 1u)) >> 16;
    float fm = __uint_as_float(mb << 16);
    float r2 = r1 - fm;                      // exact
    uint u2 = __float_as_uint(r2);
    uint lb = (u2 + 0x7FFFu + ((u2 >> 16) & 1u)) >> 16;
    h = (ushort)hb; m = (ushort)mb; l = (ushort)lb;
}

// ---------------- ||z||^2 per row ----------------
__global__ void znorm_kernel(const float* __restrict__ z, float* __restrict__ znorm) {
    const int wave = (blockIdx.x * blockDim.x + threadIdx.x) >> 6;
    const int lane = threadIdx.x & 63;
    if (wave >= N_ROWS) return;
    const float* row = z + (size_t)wave * DIM;
    float s = 0.f;
#pragma unroll
    for (int j = 0; j < 8; j++) {
        const float v = row[lane + j * 64];
        s = fmaf(v, v, s);
    }
#pragma unroll
    for (int off = 32; off; off >>= 1) s += __shfl_down(s, off, 64);
    if (lane == 0) znorm[wave] = s;
}

// ---------------- 3-way split into GRANULE layout ----------------
// Granule layout (per term): [group g = row/16][kc = k/32][granule = koct*16 + row%16][8 bf16]
// so that global_load_lds dest (base + lane*16B) == src (base + lane*16B): fully coalesced.
__global__ void split3g_kernel(const float* __restrict__ src, ushort* __restrict__ dh,
                               ushort* __restrict__ dm, ushort* __restrict__ dl, int rows) {
    const int id = blockIdx.x * 256 + threadIdx.x;  // rows*64 granules
    if (id >= rows * 64) return;
    const int row = id >> 6, k8 = id & 63;
    const int g = row >> 4, r15 = row & 15, kc = k8 >> 2, koct = k8 & 3;
    const float4 v0 = *reinterpret_cast<const float4*>(&src[(size_t)row * DIM + k8 * 8]);
    const float4 v1 = *reinterpret_cast<const float4*>(&src[(size_t)row * DIM + k8 * 8 + 4]);
    const float f[8] = {v0.x, v0.y, v0.z, v0.w, v1.x, v1.y, v1.z, v1.w};
    u16x8 h8, m8, l8;
#pragma unroll
    for (int j = 0; j < 8; j++) {
        ushort h, m, l;
        bsplit3(f[j], h, m, l);
        h8[j] = h; m8[j] = m; l8[j] = l;
    }
    const size_t off = ((((size_t)g * 16 + kc) * 64) + (koct * 16 + r15)) * 8;
    *reinterpret_cast<u16x8*>(&dh[off]) = h8;
    *reinterpret_cast<u16x8*>(&dm[off]) = m8;
    *reinterpret_cast<u16x8*>(&dl[off]) = l8;
}

// ---------------- emb 3-way bf16 split, ROW-MAJOR (mid path) ----------------
__global__ void emb_split_kernel(const float* __restrict__ emb, ushort* __restrict__ eh,
                                 ushort* __restrict__ em, ushort* __restrict__ el) {
    const size_t g = (size_t)blockIdx.x * blockDim.x + threadIdx.x;  // < 1048576 float4s
    const float4 v = reinterpret_cast<const float4*>(emb)[g];
    ushort h[4], m[4], l[4];
    bsplit3(v.x, h[0], m[0], l[0]);
    bsplit3(v.y, h[1], m[1], l[1]);
    bsplit3(v.z, h[2], m[2], l[2]);
    bsplit3(v.w, h[3], m[3], l[3]);
    reinterpret_cast<ushort4*>(eh)[g] = make_ushort4(h[0], h[1], h[2], h[3]);
    reinterpret_cast<ushort4*>(em)[g] = make_ushort4(m[0], m[1], m[2], m[3]);
    reinterpret_cast<ushort4*>(el)[g] = make_ushort4(l[0], l[1], l[2], l[3]);
}

// ---------------- BIG PATH: all-presplit MFMA argmin ----------------
// Block: 128 rows x 2048 codes (slice q of 4), 4 waves in 2x2 of 64x64 tiles.
// All staging via global_load_lds from granule-layout bf16 arrays.
#define MBLK 128
#define NBLK 128
#define QCODES 2048

__launch_bounds__(256, 2)
__global__ void argmin_mfma2_kernel(const ushort* __restrict__ zh, const ushort* __restrict__ zm,
                                    const ushort* __restrict__ zl,
                                    const ushort* __restrict__ eh, const ushort* __restrict__ em,
                                    const ushort* __restrict__ el,
                                    const float* __restrict__ znorm,
                                    float* __restrict__ cand_val, int* __restrict__ cand_idx) {
    __shared__ __align__(16) ushort A_lds[3][8][64][8];
    __shared__ __align__(16) ushort B_lds[3][8][64][8];
    __shared__ float mvals[2][2][64];
    __shared__ int   midxs[2][2][64];

    const int tid = threadIdx.x;
    const int w = tid >> 6;
    const int lane = tid & 63;
    const int lane16 = lane & 15;
    const int lq = lane >> 4;
    const int m0 = blockIdx.x * MBLK;
    const int q = blockIdx.y;
    const int wm = (w >> 1) * 64;
    const int wn = (w & 1) * 64;

    const ushort* zsp[3] = {zh, zm, zl};
    const ushort* esp[3] = {eh, em, el};

    float zn[16];
#pragma unroll
    for (int im = 0; im < 4; im++)
#pragma unroll
        for (int r = 0; r < 4; r++)
            zn[im * 4 + r] = znorm[m0 + wm + im * 16 + lq * 4 + r];

    float bestv[16];
    int besti[16];
#pragma unroll
    for (int s = 0; s < 16; s++) { bestv[s] = INFINITY; besti[s] = 0; }

    for (int nt = 0; nt < QCODES / NBLK; nt++) {
        const int n0 = q * QCODES + nt * NBLK;
        f32x4 acc[4][4];
#pragma unroll
        for (int im = 0; im < 4; im++)
#pragma unroll
            for (int in = 0; in < 4; in++)
                acc[im][in] = (f32x4){0.f, 0.f, 0.f, 0.f};

        for (int kc = 0; kc < DIM / 32; kc++) {
            // each wave stages 6 of the 24 (term,group) pairs for A and for B
#pragma unroll
            for (int c = 0; c < 6; c++) {
                const int pg = w + c * 4;
                const int t = pg >> 3, g = pg & 7;
                const ushort* srcA = zsp[t] +
                    ((((size_t)(m0 >> 4) + g) * 16 + kc) * 64 + lane) * 8;
                __builtin_amdgcn_global_load_lds(
                    (const __attribute__((address_space(1))) void*)srcA,
                    (__attribute__((address_space(3))) void*)&A_lds[t][g][0][0],
                    16, 0, 0);
                const ushort* srcB = esp[t] +
                    ((((size_t)(n0 >> 4) + g) * 16 + kc) * 64 + lane) * 8;
                __builtin_amdgcn_global_load_lds(
                    (const __attribute__((address_space(1))) void*)srcB,
                    (__attribute__((address_space(3))) void*)&B_lds[t][g][0][0],
                    16, 0, 0);
            }
            __syncthreads();
            bf16x8 bfr[3][4];
#pragma unroll
            for (int t = 0; t < 3; t++)
#pragma unroll
                for (int in = 0; in < 4; in++)
                    bfr[t][in] = *reinterpret_cast<const bf16x8*>(&B_lds[t][(wn >> 4) + in][lane][0]);
#pragma unroll
            for (int t = 0; t < 3; t++) {
                bf16x8 afr[4];
#pragma unroll
                for (int im = 0; im < 4; im++)
                    afr[im] = *reinterpret_cast<const bf16x8*>(&A_lds[t][(wm >> 4) + im][lane][0]);
                // term pairs: (h,*): hh,hm,hl ; (m,*): mh,mm ; (l,*): lh -> 6 total
#pragma unroll
                for (int u = 0; u < 3 - t; u++)
#pragma unroll
                    for (int im = 0; im < 4; im++)
#pragma unroll
                        for (int in = 0; in < 4; in++)
                            acc[im][in] = __builtin_amdgcn_mfma_f32_16x16x32_bf16(
                                afr[im], bfr[u][in], acc[im][in], 0, 0, 0);
            }
            __syncthreads();
        }
        // epilogue: t = fl(zn - 2*dot), running first-min (ascending code order)
#pragma unroll
        for (int im = 0; im < 4; im++)
#pragma unroll
            for (int r = 0; r < 4; r++) {
                const int s = im * 4 + r;
#pragma unroll
                for (int in = 0; in < 4; in++) {
                    const float dv = fmaf(-2.f, acc[im][in][r], zn[s]);
                    const int code = n0 + wn + in * 16 + lane16;
                    if (dv < bestv[s]) { bestv[s] = dv; besti[s] = code; }
                }
            }
    }
    // cross-lane reduce over the 16 lanes (same lq) sharing each row
#pragma unroll
    for (int s = 0; s < 16; s++) {
        float bv = bestv[s];
        int bi = besti[s];
#pragma unroll
        for (int off = 1; off < 16; off <<= 1) {
            const float v2 = __shfl_xor(bv, off, 64);
            const int i2 = __shfl_xor(bi, off, 64);
            if (v2 < bv || (v2 == bv && i2 < bi)) { bv = v2; bi = i2; }
        }
        if (lane16 == 0) {
            const int im = s >> 2, r = s & 3;
            const int rloc = im * 16 + lq * 4 + r;
            mvals[w >> 1][w & 1][rloc] = bv;
            midxs[w >> 1][w & 1][rloc] = bi;
        }
    }
    __syncthreads();
    if (tid < 128) {
        const int wp = tid >> 6, rl = tid & 63;
        const float v0 = mvals[wp][0][rl], v1 = mvals[wp][1][rl];
        const int i0 = midxs[wp][0][rl], i1 = midxs[wp][1][rl];
        float bv; int bi;
        if (v1 < v0 || (v1 == v0 && i1 < i0)) { bv = v1; bi = i1; }
        else { bv = v0; bi = i0; }
        const int row = m0 + wp * 64 + rl;
        cand_val[(size_t)q * N_ROWS + row] = bv;
        cand_idx[(size_t)q * N_ROWS + row] = bi;
    }
}

// ---------------- MID PATH: R5 kernel (in-loop z split), proven ----------------
__launch_bounds__(256, 2)
__global__ void argmin_mfma_kernel(const float* __restrict__ z,
                                   const ushort* __restrict__ eh,
                                   const ushort* __restrict__ em,
                                   const ushort* __restrict__ el,
                                   const float* __restrict__ znorm,
                                   float* __restrict__ cand_val, int* __restrict__ cand_idx) {
    __shared__ __align__(16) ushort A_lds[3][8][64][8];
    __shared__ __align__(16) ushort B_lds[3][8][64][8];
    __shared__ float mvals[2][2][64];
    __shared__ int   midxs[2][2][64];

    const int tid = threadIdx.x;
    const int w = tid >> 6;
    const int lane = tid & 63;
    const int lane16 = lane & 15;
    const int lq = lane >> 4;
    const int m0 = blockIdx.x * MBLK;
    const int q = blockIdx.y;
    const int wm = (w >> 1) * 64;
    const int wn = (w & 1) * 64;

    const ushort* esp[3] = {eh, em, el};

    float zn[16];
#pragma unroll
    for (int im = 0; im < 4; im++)
#pragma unroll
        for (int r = 0; r < 4; r++)
            zn[im * 4 + r] = znorm[m0 + wm + im * 16 + lq * 4 + r];

    float bestv[16];
    int besti[16];
#pragma unroll
    for (int s = 0; s < 16; s++) { bestv[s] = INFINITY; besti[s] = 0; }

    for (int nt = 0; nt < QCODES / NBLK; nt++) {
        const int n0 = q * QCODES + nt * NBLK;
        f32x4 acc[4][4];
#pragma unroll
        for (int im = 0; im < 4; im++)
#pragma unroll
            for (int in = 0; in < 4; in++)
                acc[im][in] = (f32x4){0.f, 0.f, 0.f, 0.f};

        for (int kc = 0; kc < DIM / 32; kc++) {
            const int k0 = kc * 32;
#pragma unroll
            for (int c = 0; c < 6; c++) {
                const int pg = w + c * 4;
                const int t = pg >> 3, g = pg & 7;
                const ushort* src = esp[t] +
                    ((size_t)(n0 + g * 16 + lane16) * DIM + k0 + lq * 8);
                __builtin_amdgcn_global_load_lds(
                    (const __attribute__((address_space(1))) void*)src,
                    (__attribute__((address_space(3))) void*)&B_lds[t][g][0][0],
                    16, 0, 0);
            }
#pragma unroll
            for (int p = 0; p < 4; p++) {
                const int li = p * 256 + tid;
                const int m = li >> 3, k4 = li & 7;
                const float4 v = *reinterpret_cast<const float4*>(
                    &z[(size_t)(m0 + m) * DIM + k0 + k4 * 4]);
                ushort h[4], mm[4], ll[4];
                bsplit3(v.x, h[0], mm[0], ll[0]);
                bsplit3(v.y, h[1], mm[1], ll[1]);
                bsplit3(v.z, h[2], mm[2], ll[2]);
                bsplit3(v.w, h[3], mm[3], ll[3]);
                const int g = m >> 4, gr = (k4 >> 1) * 16 + (m & 15), j0 = (k4 & 1) * 4;
                *reinterpret_cast<ushort4*>(&A_lds[0][g][gr][j0]) = make_ushort4(h[0], h[1], h[2], h[3]);
                *reinterpret_cast<ushort4*>(&A_lds[1][g][gr][j0]) = make_ushort4(mm[0], mm[1], mm[2], mm[3]);
                *reinterpret_cast<ushort4*>(&A_lds[2][g][gr][j0]) = make_ushort4(ll[0], ll[1], ll[2], ll[3]);
            }
            __syncthreads();
            bf16x8 bfr[3][4];
#pragma unroll
            for (int t = 0; t < 3; t++)
#pragma unroll
                for (int in = 0; in < 4; in++)
                    bfr[t][in] = *reinterpret_cast<const bf16x8*>(&B_lds[t][(wn >> 4) + in][lane][0]);
#pragma unroll
            for (int t = 0; t < 3; t++) {
                bf16x8 afr[4];
#pragma unroll
                for (int im = 0; im < 4; im++)
                    afr[im] = *reinterpret_cast<const bf16x8*>(&A_lds[t][(wm >> 4) + im][lane][0]);
#pragma unroll
                for (int u = 0; u < 3 - t; u++)
#pragma unroll
                    for (int im = 0; im < 4; im++)
#pragma unroll
                        for (int in = 0; in < 4; in++)
                            acc[im][in] = __builtin_amdgcn_mfma_f32_16x16x32_bf16(
                                afr[im], bfr[u][in], acc[im][in], 0, 0, 0);
            }
            __syncthreads();
        }
#pragma unroll
        for (int im = 0; im < 4; im++)
#pragma unroll
            for (int r = 0; r < 4; r++) {
                const int s = im * 4 + r;
#pragma unroll
                for (int in = 0; in < 4; in++) {
                    const float dv = fmaf(-2.f, acc[im][in][r], zn[s]);
                    const int code = n0 + wn + in * 16 + lane16;
                    if (dv < bestv[s]) { bestv[s] = dv; besti[s] = code; }
                }
            }
    }
#pragma unroll
    for (int s = 0; s < 16; s++) {
        float bv = bestv[s];
        int bi = besti[s];
#pragma unroll
        for (int off = 1; off < 16; off <<= 1) {
            const float v2 = __shfl_xor(bv, off, 64);
            const int i2 = __shfl_xor(bi, off, 64);
            if (v2 < bv || (v2 == bv && i2 < bi)) { bv = v2; bi = i2; }
        }
        if (lane16 == 0) {
            const int im = s >> 2, r = s & 3;
            const int rloc = im * 16 + lq * 4 + r;
            mvals[w >> 1][w & 1][rloc] = bv;
            midxs[w >> 1][w & 1][rloc] = bi;
        }
    }
    __syncthreads();
    if (tid < 128) {
        const int wp = tid >> 6, rl = tid & 63;
        const float v0 = mvals[wp][0][rl], v1 = mvals[wp][1][rl];
        const int i0 = midxs[wp][0][rl], i1 = midxs[wp][1][rl];
        float bv; int bi;
        if (v1 < v0 || (v1 == v0 && i1 < i0)) { bv = v1; bi = i1; }
        else { bv = v0; bi = i0; }
        const int row = m0 + wp * 64 + rl;
        cand_val[(size_t)q * N_ROWS + row] = bv;
        cand_idx[(size_t)q * N_ROWS + row] = bi;
    }
}

// ---------------- fallback fp32 vector argmin (R2, proven) ----------------
#define MT 64
#define ET 128
#define KT 16
__launch_bounds__(256, 2)
__global__ void argmin_vec_kernel(const float* __restrict__ z, const float* __restrict__ emb,
                                  const float* __restrict__ znorm,
                                  float* __restrict__ cand_val, int* __restrict__ cand_idx) {
    __shared__ float As[KT][68];
    __shared__ float Bs[KT][132];
    __shared__ float rv[MT][17];
    __shared__ int ri[MT][17];
    const int tid = threadIdx.x;
    const int tx = tid & 15;
    const int ty = tid >> 4;
    const int m0 = blockIdx.x * MT;
    const int ebase = blockIdx.y * (NE / 2);
    float zn[4];
#pragma unroll
    for (int r = 0; r < 4; r++) zn[r] = znorm[m0 + ty * 4 + r];
    float bestv[4]; int besti[4];
#pragma unroll
    for (int r = 0; r < 4; r++) { bestv[r] = INFINITY; besti[r] = 0; }
    const int k4 = tid & 3;
    const int ldrow = tid >> 2;
    for (int et = 0; et < (NE / 2) / ET; ++et) {
        const int e0 = ebase + et * ET;
        float acc[4][8];
#pragma unroll
        for (int r = 0; r < 4; r++)
#pragma unroll
            for (int c = 0; c < 8; c++) acc[r][c] = 0.f;
        for (int kt = 0; kt < DIM / KT; ++kt) {
            {
                const float4 v = *reinterpret_cast<const float4*>(
                    &z[(size_t)(m0 + ldrow) * DIM + kt * KT + k4 * 4]);
                As[k4 * 4 + 0][ldrow] = v.x; As[k4 * 4 + 1][ldrow] = v.y;
                As[k4 * 4 + 2][ldrow] = v.z; As[k4 * 4 + 3][ldrow] = v.w;
            }
#pragma unroll
            for (int i = 0; i < 2; i++) {
                const int code = ldrow + i * 64;
                const float4 v = *reinterpret_cast<const float4*>(
                    &emb[(size_t)(e0 + code) * DIM + kt * KT + k4 * 4]);
                Bs[k4 * 4 + 0][code] = v.x; Bs[k4 * 4 + 1][code] = v.y;
                Bs[k4 * 4 + 2][code] = v.z; Bs[k4 * 4 + 3][code] = v.w;
            }
            __syncthreads();
#pragma unroll
            for (int kk = 0; kk < KT; kk++) {
                const float4 a = *reinterpret_cast<const float4*>(&As[kk][ty * 4]);
                const float4 b0 = *reinterpret_cast<const float4*>(&Bs[kk][tx * 4]);
                const float4 b1 = *reinterpret_cast<const float4*>(&Bs[kk][64 + tx * 4]);
                const float av[4] = {a.x, a.y, a.z, a.w};
                const float bv[8] = {b0.x, b0.y, b0.z, b0.w, b1.x, b1.y, b1.z, b1.w};
#pragma unroll
                for (int r = 0; r < 4; r++)
#pragma unroll
                    for (int c = 0; c < 8; c++)
                        acc[r][c] = fmaf(av[r], bv[c], acc[r][c]);
            }
            __syncthreads();
        }
#pragma unroll
        for (int c = 0; c < 8; c++) {
            const int lc = (c < 4) ? (tx * 4 + c) : (64 + tx * 4 + (c - 4));
            const int gidx = e0 + lc;
#pragma unroll
            for (int r = 0; r < 4; r++) {
                const float t = fmaf(-2.f, acc[r][c], zn[r]);
                if (t < bestv[r]) { bestv[r] = t; besti[r] = gidx; }
            }
        }
    }
#pragma unroll
    for (int r = 0; r < 4; r++) { rv[ty * 4 + r][tx] = bestv[r]; ri[ty * 4 + r][tx] = besti[r]; }
    __syncthreads();
    if (tid < MT) {
        float bv = rv[tid][0]; int bi = ri[tid][0];
#pragma unroll
        for (int t = 1; t < 16; t++) {
            const float v = rv[tid][t]; const int i = ri[tid][t];
            if (v < bv || (v == bv && i < bi)) { bv = v; bi = i; }
        }
        cand_val[(size_t)blockIdx.y * N_ROWS + m0 + tid] = bv;
        cand_idx[(size_t)blockIdx.y * N_ROWS + m0 + tid] = bi;
    }
}

// ---------------- finalize: pick idx over nq candidates, gather, loss ----
__global__ void finalize_kernel(const float* __restrict__ z, const float* __restrict__ emb,
                                const float* __restrict__ cand_val, const int* __restrict__ cand_idx,
                                int nq, float* __restrict__ out, int* __restrict__ hist,
                                float* __restrict__ lossbuf) {
    __shared__ float sdata[256];
    const int n = blockIdx.x;
    float v = cand_val[n];
    int idx = cand_idx[n];
    for (int qq = 1; qq < nq; qq++) {
        const float vq = cand_val[(size_t)qq * N_ROWS + n];
        const int iq = cand_idx[(size_t)qq * N_ROWS + n];
        if (vq < v || (vq == v && iq < idx)) { v = vq; idx = iq; }
    }
    const float* e = emb + (size_t)idx * DIM;
    const float* zr = z + (size_t)n * DIM;
    const int tid = threadIdx.x;
    float ls = 0.f;
#pragma unroll
    for (int j = 0; j < 2; j++) {
        const int k = tid + j * 256;
        const float zq = e[k];
        const float zv = zr[k];
        const float d = zq - zv;
        out[ZQ_OFF + (size_t)n * DIM + k] = zv + d;  // match ref rounding: z + (z_q - z)
        ls += d * d;
    }
    sdata[tid] = ls;
    __syncthreads();
    for (int s = 128; s; s >>= 1) {
        if (tid < s) sdata[tid] += sdata[tid + s];
        __syncthreads();
    }
    if (tid == 0) {
        atomicAdd(lossbuf + (n & 255), sdata[0]);
        atomicAdd(hist + idx, 1);
        out[ME_OFF + (size_t)n * NE + idx] = 1.0f;
        out[IDX_OFF + n] = (float)idx;
    }
}

// ---------------- perplexity + final loss ----------------
__global__ void perp_kernel(const int* __restrict__ hist, const float* __restrict__ lossbuf,
                            float* __restrict__ out) {
    __shared__ float sdata[256];
    const int tid = threadIdx.x;
    float s = 0.f;
    for (int b = tid; b < NE; b += 256) {
        const float p = (float)hist[b] * (1.0f / 16384.f);
        s += p * logf(p + 1e-10f);
    }
    sdata[tid] = s;
    __syncthreads();
    for (int st = 128; st; st >>= 1) {
        if (tid < st) sdata[tid] += sdata[tid + st];
        __syncthreads();
    }
    if (tid == 0) out[PERP_OFF] = expf(-sdata[0]);
    __syncthreads();
    sdata[tid] = lossbuf[tid];
    __syncthreads();
    for (int st = 128; st; st >>= 1) {
        if (tid < st) sdata[tid] += sdata[tid + st];
        __syncthreads();
    }
    if (tid == 0) out[LOSS_OFF] = sdata[0] * (1.25f / 8388608.f);
}

extern "C" void kernel_launch(void* const* d_in, const int* in_sizes, int n_in,
                              void* d_out, int out_size, void* d_ws, size_t ws_size,
                              hipStream_t stream) {
    const float* z = (const float*)d_in[0];    // [32,512,512]
    const float* emb = (const float*)d_in[1];  // [8192,512]
    float* out = (float*)d_out;
    unsigned char* w = (unsigned char*)d_ws;

    const size_t ZSP = 16777216UL;  // one z split term (16384*512*2 B)
    const size_t ESP = 8388608UL;   // one emb split term (8192*512*2 B)

    // big-path layout (names avoid libc macros like M_E!)
    const size_t OB_Z = 0;
    const size_t OB_E = 3 * ZSP;
    const size_t OB_ZN = OB_E + 3 * ESP;
    const size_t OB_CV = OB_ZN + 65536;
    const size_t OB_CI = OB_CV + 262144;
    const size_t OB_H = OB_CI + 262144;
    const size_t OB_LB = OB_H + 32768;
    const size_t NEED_BIG = OB_LB + 1024;
    // mid-path layout
    const size_t OM_E = 0;
    const size_t OM_ZN = 3 * ESP;
    const size_t OM_CV = OM_ZN + 65536;
    const size_t OM_CI = OM_CV + 262144;
    const size_t OM_H = OM_CI + 262144;
    const size_t OM_LB = OM_H + 32768;
    const size_t NEED_MID = OM_LB + 1024;

    // min_encodings zero-fill (536 MB) as a graph memset node
    (void)hipMemsetAsync((void*)(out + ME_OFF), 0, 134217728UL * 4, stream);

    if (ws_size >= NEED_BIG) {
        ushort* zh = (ushort*)(w + OB_Z);
        ushort* zm = (ushort*)(w + OB_Z + ZSP);
        ushort* zl = (ushort*)(w + OB_Z + 2 * ZSP);
        ushort* eh = (ushort*)(w + OB_E);
        ushort* em = (ushort*)(w + OB_E + ESP);
        ushort* el = (ushort*)(w + OB_E + 2 * ESP);
        float* znorm = (float*)(w + OB_ZN);
        float* cand_val = (float*)(w + OB_CV);
        int* cand_idx = (int*)(w + OB_CI);
        int* hist = (int*)(w + OB_H);
        float* lossbuf = (float*)(w + OB_LB);

        (void)hipMemsetAsync(hist, 0, 32768, stream);
        (void)hipMemsetAsync(lossbuf, 0, 1024, stream);
        hipLaunchKernelGGL(split3g_kernel, dim3(N_ROWS * 64 / 256), dim3(256), 0, stream,
                           z, zh, zm, zl, N_ROWS);
        hipLaunchKernelGGL(split3g_kernel, dim3(NE * 64 / 256), dim3(256), 0, stream,
                           emb, eh, em, el, NE);
        hipLaunchKernelGGL(znorm_kernel, dim3(4096), dim3(256), 0, stream, z, znorm);
        hipLaunchKernelGGL(argmin_mfma2_kernel, dim3(N_ROWS / MBLK, 4), dim3(256), 0, stream,
                           zh, zm, zl, eh, em, el, znorm, cand_val, cand_idx);
        hipLaunchKernelGGL(finalize_kernel, dim3(N_ROWS), dim3(256), 0, stream,
                           z, emb, cand_val, cand_idx, 4, out, hist, lossbuf);
        hipLaunchKernelGGL(perp_kernel, dim3(1), dim3(256), 0, stream, hist, lossbuf, out);
    } else if (ws_size >= NEED_MID) {
        ushort* eh = (ushort*)(w + OM_E);
        ushort* em = (ushort*)(w + OM_E + ESP);
        ushort* el = (ushort*)(w + OM_E + 2 * ESP);
        float* znorm = (float*)(w + OM_ZN);
        float* cand_val = (float*)(w + OM_CV);
        int* cand_idx = (int*)(w + OM_CI);
        int* hist = (int*)(w + OM_H);
        float* lossbuf = (float*)(w + OM_LB);

        (void)hipMemsetAsync(hist, 0, 32768, stream);
        (void)hipMemsetAsync(lossbuf, 0, 1024, stream);
        hipLaunchKernelGGL(emb_split_kernel, dim3(4096), dim3(256), 0, stream, emb, eh, em, el);
        hipLaunchKernelGGL(znorm_kernel, dim3(4096), dim3(256), 0, stream, z, znorm);
        hipLaunchKernelGGL(argmin_mfma_kernel, dim3(N_ROWS / MBLK, 4), dim3(256), 0, stream,
                           z, eh, em, el, znorm, cand_val, cand_idx);
        hipLaunchKernelGGL(finalize_kernel, dim3(N_ROWS), dim3(256), 0, stream,
                           z, emb, cand_val, cand_idx, 4, out, hist, lossbuf);
        hipLaunchKernelGGL(perp_kernel, dim3(1), dim3(256), 0, stream, hist, lossbuf, out);
    } else {
        float* znorm = (float*)w;
        float* cand_val = (float*)(w + 65536);
        int* cand_idx = (int*)(w + 65536 + 131072);
        int* hist = (int*)(w + 65536 + 262144);
        float* lossbuf = (float*)(w + 65536 + 262144 + 32768);

        (void)hipMemsetAsync(hist, 0, 32768, stream);
        (void)hipMemsetAsync(lossbuf, 0, 1024, stream);
        hipLaunchKernelGGL(znorm_kernel, dim3(4096), dim3(256), 0, stream, z, znorm);
        hipLaunchKernelGGL(argmin_vec_kernel, dim3(N_ROWS / MT, 2), dim3(256), 0, stream,
                           z, emb, znorm, cand_val, cand_idx);
        hipLaunchKernelGGL(finalize_kernel, dim3(N_ROWS), dim3(256), 0, stream,
                           z, emb, cand_val, cand_idx, 2, out, hist, lossbuf);
        hipLaunchKernelGGL(perp_kernel, dim3(1), dim3(256), 0, stream, hist, lossbuf, out);
    }
}

// Round 9
// 1139.844 us; speedup vs baseline: 2.3127x; 1.0920x over previous
//
#include <hip/hip_runtime.h>
#include <math.h>

#define N_ROWS 16384
#define DIM 512
#define NE 8192

// d_out layout (floats), reference return order:
// loss[1], z_q_st[32*512*512], perplexity[1], min_encodings[16384*8192], idx[16384]
#define LOSS_OFF 0UL
#define ZQ_OFF 1UL
#define PERP_OFF 8388609UL
#define ME_OFF 8388610UL
#define IDX_OFF 142606338UL
#define ZF4_TOTAL 33554431UL   // f32x4 count in one-hot region after 2-float head

typedef __attribute__((ext_vector_type(8))) short bf16x8;
typedef __attribute__((ext_vector_type(8))) unsigned short u16x8;
typedef __attribute__((ext_vector_type(4))) float f32x4;

// 3-way bf16 split (RNE): f = h + m + l + eps, |eps| <~ 2^-27 |f|
__device__ __forceinline__ void bsplit3(float f, ushort& h, ushort& m, ushort& l) {
    uint u = __float_as_uint(f);
    uint hb = (u + 0x7FFFu + ((u >> 16) & 1u)) >> 16;
    float fh = __uint_as_float(hb << 16);
    float r1 = f - fh;                       // exact (Sterbenz)
    uint u1 = __float_as_uint(r1);
    uint mb = (u1 + 0x7FFFu + ((u1 >> 16) & 1u)) >> 16;
    float fm = __uint_as_float(mb << 16);
    float r2 = r1 - fm;                      // exact
    uint u2 = __float_as_uint(r2);
    uint lb = (u2 + 0x7FFFu + ((u2 >> 16) & 1u)) >> 16;
    h = (ushort)hb; m = (ushort)mb; l = (ushort)lb;
}

// ---------------- ||z||^2 per row (mid/vec paths) ----------------
__global__ void znorm_kernel(const float* __restrict__ z, float* __restrict__ znorm) {
    const int wave = (blockIdx.x * blockDim.x + threadIdx.x) >> 6;
    const int lane = threadIdx.x & 63;
    if (wave >= N_ROWS) return;
    const float* row = z + (size_t)wave * DIM;
    float s = 0.f;
#pragma unroll
    for (int j = 0; j < 8; j++) {
        const float v = row[lane + j * 64];
        s = fmaf(v, v, s);
    }
#pragma unroll
    for (int off = 32; off; off >>= 1) s += __shfl_down(s, off, 64);
    if (lane == 0) znorm[wave] = s;
}

// ---------------- 3-way split into GRANULE layout (+ optional row norms) ----
// Granule layout (per term): [g = row/16][kc = k/32][granule = koct*16 + row%16][8 bf16]
// so that global_load_lds dest (base + lane*16B) == src (base + lane*16B).
__global__ void split3g_kernel(const float* __restrict__ src, ushort* __restrict__ dh,
                               ushort* __restrict__ dm, ushort* __restrict__ dl,
                               float* __restrict__ nrm, int rows) {
    const int id = blockIdx.x * 256 + threadIdx.x;  // rows*64 granules
    if (id >= rows * 64) return;
    const int row = id >> 6, k8 = id & 63;
    const int g = row >> 4, r15 = row & 15, kc = k8 >> 2, koct = k8 & 3;
    const float4 v0 = *reinterpret_cast<const float4*>(&src[(size_t)row * DIM + k8 * 8]);
    const float4 v1 = *reinterpret_cast<const float4*>(&src[(size_t)row * DIM + k8 * 8 + 4]);
    const float f[8] = {v0.x, v0.y, v0.z, v0.w, v1.x, v1.y, v1.z, v1.w};
    u16x8 h8, m8, l8;
    float s = 0.f;
#pragma unroll
    for (int j = 0; j < 8; j++) {
        ushort h, m, l;
        bsplit3(f[j], h, m, l);
        h8[j] = h; m8[j] = m; l8[j] = l;
        s = fmaf(f[j], f[j], s);
    }
    const size_t off = ((((size_t)g * 16 + kc) * 64) + (koct * 16 + r15)) * 8;
    *reinterpret_cast<u16x8*>(&dh[off]) = h8;
    *reinterpret_cast<u16x8*>(&dm[off]) = m8;
    *reinterpret_cast<u16x8*>(&dl[off]) = l8;
    if (nrm) {  // 64 consecutive tids = one row = one wave
        const int lane = threadIdx.x & 63;
#pragma unroll
        for (int o = 32; o; o >>= 1) s += __shfl_down(s, o, 64);
        if (lane == 0) nrm[row] = s;
    }
}

// ---------------- emb 3-way bf16 split, ROW-MAJOR (mid path) ----------------
__global__ void emb_split_kernel(const float* __restrict__ emb, ushort* __restrict__ eh,
                                 ushort* __restrict__ em, ushort* __restrict__ el) {
    const size_t g = (size_t)blockIdx.x * blockDim.x + threadIdx.x;
    const float4 v = reinterpret_cast<const float4*>(emb)[g];
    ushort h[4], m[4], l[4];
    bsplit3(v.x, h[0], m[0], l[0]);
    bsplit3(v.y, h[1], m[1], l[1]);
    bsplit3(v.z, h[2], m[2], l[2]);
    bsplit3(v.w, h[3], m[3], l[3]);
    reinterpret_cast<ushort4*>(eh)[g] = make_ushort4(h[0], h[1], h[2], h[3]);
    reinterpret_cast<ushort4*>(em)[g] = make_ushort4(m[0], m[1], m[2], m[3]);
    reinterpret_cast<ushort4*>(el)[g] = make_ushort4(l[0], l[1], l[2], l[3]);
}

// ---------------- BIG PATH: 6-term presplit MFMA argmin + fused zeroing -----
// Block: 128 rows x 2048 codes (slice q of 4), 4 waves in 2x2 of 64x64 tiles.
// Terms: hh,hm,hl, mh,mm, lh (R7-proven: 0 idx flips). Each block also zeroes
// exactly 1 MB of the one-hot region (1 NT f32x4/thread/kc; no overlap).
#define MBLK 128
#define NBLK 128
#define QCODES 2048

__launch_bounds__(256, 2)
__global__ void argmin_mfma2z_kernel(const ushort* __restrict__ zh, const ushort* __restrict__ zm,
                                     const ushort* __restrict__ zl,
                                     const ushort* __restrict__ eh, const ushort* __restrict__ em,
                                     const ushort* __restrict__ el,
                                     const float* __restrict__ znorm, float* __restrict__ out,
                                     float* __restrict__ cand_val, int* __restrict__ cand_idx) {
    __shared__ __align__(16) ushort A_lds[3][8][64][8];
    __shared__ __align__(16) ushort B_lds[3][8][64][8];
    __shared__ float mvals[2][2][64];
    __shared__ int   midxs[2][2][64];

    const int tid = threadIdx.x;
    const int w = tid >> 6;
    const int lane = tid & 63;
    const int lane16 = lane & 15;
    const int lq = lane >> 4;
    const int m0 = blockIdx.x * MBLK;
    const int q = blockIdx.y;
    const int wm = (w >> 1) * 64;
    const int wn = (w & 1) * 64;
    const int b = q * gridDim.x + blockIdx.x;  // 0..511

    const ushort* zsp[3] = {zh, zm, zl};
    const ushort* esp[3] = {eh, em, el};

    f32x4* zf = reinterpret_cast<f32x4*>(out + ME_OFF + 2);
    const f32x4 zero4 = (f32x4){0.f, 0.f, 0.f, 0.f};
    if (b == 0 && tid == 0) { out[ME_OFF] = 0.f; out[ME_OFF + 1] = 0.f; }
    if (b == 511 && tid == 0) {
        out[ME_OFF + 2 + 4 * ZF4_TOTAL] = 0.f;
        out[ME_OFF + 2 + 4 * ZF4_TOTAL + 1] = 0.f;
    }

    float zn[16];
#pragma unroll
    for (int im = 0; im < 4; im++)
#pragma unroll
        for (int r = 0; r < 4; r++)
            zn[im * 4 + r] = znorm[m0 + wm + im * 16 + lq * 4 + r];

    float bestv[16];
    int besti[16];
#pragma unroll
    for (int s = 0; s < 16; s++) { bestv[s] = INFINITY; besti[s] = 0; }

    for (int nt = 0; nt < QCODES / NBLK; nt++) {
        const int n0 = q * QCODES + nt * NBLK;
        f32x4 acc[4][4];
#pragma unroll
        for (int im = 0; im < 4; im++)
#pragma unroll
            for (int in = 0; in < 4; in++)
                acc[im][in] = (f32x4){0.f, 0.f, 0.f, 0.f};

        for (int kc = 0; kc < DIM / 32; kc++) {
            // each wave stages 6 of the 24 (term,group) pairs for A and for B
#pragma unroll
            for (int c = 0; c < 6; c++) {
                const int pg = w + c * 4;
                const int t = pg >> 3, g = pg & 7;
                const ushort* srcA = zsp[t] +
                    ((((size_t)(m0 >> 4) + g) * 16 + kc) * 64 + lane) * 8;
                __builtin_amdgcn_global_load_lds(
                    (const __attribute__((address_space(1))) void*)srcA,
                    (__attribute__((address_space(3))) void*)&A_lds[t][g][0][0],
                    16, 0, 0);
                const ushort* srcB = esp[t] +
                    ((((size_t)(n0 >> 4) + g) * 16 + kc) * 64 + lane) * 8;
                __builtin_amdgcn_global_load_lds(
                    (const __attribute__((address_space(1))) void*)srcB,
                    (__attribute__((address_space(3))) void*)&B_lds[t][g][0][0],
                    16, 0, 0);
            }
            // fused one-hot zeroing: one contiguous 4 KB wavefront store per kc
            {
                const size_t gidx = (size_t)b * 65536 + (size_t)(nt * 16 + kc) * 256 + tid;
                if (gidx < ZF4_TOTAL) __builtin_nontemporal_store(zero4, &zf[gidx]);
            }
            __syncthreads();
            bf16x8 bfr[3][4];
#pragma unroll
            for (int t = 0; t < 3; t++)
#pragma unroll
                for (int in = 0; in < 4; in++)
                    bfr[t][in] = *reinterpret_cast<const bf16x8*>(&B_lds[t][(wn >> 4) + in][lane][0]);
#pragma unroll
            for (int t = 0; t < 3; t++) {
                bf16x8 afr[4];
#pragma unroll
                for (int im = 0; im < 4; im++)
                    afr[im] = *reinterpret_cast<const bf16x8*>(&A_lds[t][(wm >> 4) + im][lane][0]);
                // term pairs: (h,*): hh,hm,hl ; (m,*): mh,mm ; (l,*): lh -> 6 total
#pragma unroll
                for (int u = 0; u < 3 - t; u++)
#pragma unroll
                    for (int im = 0; im < 4; im++)
#pragma unroll
                        for (int in = 0; in < 4; in++)
                            acc[im][in] = __builtin_amdgcn_mfma_f32_16x16x32_bf16(
                                afr[im], bfr[u][in], acc[im][in], 0, 0, 0);
            }
            __syncthreads();
        }
        // epilogue: t = fl(zn - 2*dot), running first-min (ascending code order)
#pragma unroll
        for (int im = 0; im < 4; im++)
#pragma unroll
            for (int r = 0; r < 4; r++) {
                const int s = im * 4 + r;
#pragma unroll
                for (int in = 0; in < 4; in++) {
                    const float dv = fmaf(-2.f, acc[im][in][r], zn[s]);
                    const int code = n0 + wn + in * 16 + lane16;
                    if (dv < bestv[s]) { bestv[s] = dv; besti[s] = code; }
                }
            }
    }
    // cross-lane reduce over the 16 lanes (same lq) sharing each row
#pragma unroll
    for (int s = 0; s < 16; s++) {
        float bv = bestv[s];
        int bi = besti[s];
#pragma unroll
        for (int off = 1; off < 16; off <<= 1) {
            const float v2 = __shfl_xor(bv, off, 64);
            const int i2 = __shfl_xor(bi, off, 64);
            if (v2 < bv || (v2 == bv && i2 < bi)) { bv = v2; bi = i2; }
        }
        if (lane16 == 0) {
            const int im = s >> 2, r = s & 3;
            const int rloc = im * 16 + lq * 4 + r;
            mvals[w >> 1][w & 1][rloc] = bv;
            midxs[w >> 1][w & 1][rloc] = bi;
        }
    }
    __syncthreads();
    if (tid < 128) {
        const int wp = tid >> 6, rl = tid & 63;
        const float v0 = mvals[wp][0][rl], v1 = mvals[wp][1][rl];
        const int i0 = midxs[wp][0][rl], i1 = midxs[wp][1][rl];
        float bv; int bi;
        if (v1 < v0 || (v1 == v0 && i1 < i0)) { bv = v1; bi = i1; }
        else { bv = v0; bi = i0; }
        const int row = m0 + wp * 64 + rl;
        cand_val[(size_t)q * N_ROWS + row] = bv;
        cand_idx[(size_t)q * N_ROWS + row] = bi;
    }
}

// ---------------- MID PATH: R5/R7 6-term kernel (in-loop z split), proven ----
__launch_bounds__(256, 2)
__global__ void argmin_mfma_kernel(const float* __restrict__ z,
                                   const ushort* __restrict__ eh,
                                   const ushort* __restrict__ em,
                                   const ushort* __restrict__ el,
                                   const float* __restrict__ znorm,
                                   float* __restrict__ cand_val, int* __restrict__ cand_idx) {
    __shared__ __align__(16) ushort A_lds[3][8][64][8];
    __shared__ __align__(16) ushort B_lds[3][8][64][8];
    __shared__ float mvals[2][2][64];
    __shared__ int   midxs[2][2][64];

    const int tid = threadIdx.x;
    const int w = tid >> 6;
    const int lane = tid & 63;
    const int lane16 = lane & 15;
    const int lq = lane >> 4;
    const int m0 = blockIdx.x * MBLK;
    const int q = blockIdx.y;
    const int wm = (w >> 1) * 64;
    const int wn = (w & 1) * 64;

    const ushort* esp[3] = {eh, em, el};

    float zn[16];
#pragma unroll
    for (int im = 0; im < 4; im++)
#pragma unroll
        for (int r = 0; r < 4; r++)
            zn[im * 4 + r] = znorm[m0 + wm + im * 16 + lq * 4 + r];

    float bestv[16];
    int besti[16];
#pragma unroll
    for (int s = 0; s < 16; s++) { bestv[s] = INFINITY; besti[s] = 0; }

    for (int nt = 0; nt < QCODES / NBLK; nt++) {
        const int n0 = q * QCODES + nt * NBLK;
        f32x4 acc[4][4];
#pragma unroll
        for (int im = 0; im < 4; im++)
#pragma unroll
            for (int in = 0; in < 4; in++)
                acc[im][in] = (f32x4){0.f, 0.f, 0.f, 0.f};

        for (int kc = 0; kc < DIM / 32; kc++) {
            const int k0 = kc * 32;
#pragma unroll
            for (int c = 0; c < 6; c++) {
                const int pg = w + c * 4;
                const int t = pg >> 3, g = pg & 7;
                const ushort* src = esp[t] +
                    ((size_t)(n0 + g * 16 + lane16) * DIM + k0 + lq * 8);
                __builtin_amdgcn_global_load_lds(
                    (const __attribute__((address_space(1))) void*)src,
                    (__attribute__((address_space(3))) void*)&B_lds[t][g][0][0],
                    16, 0, 0);
            }
#pragma unroll
            for (int p = 0; p < 4; p++) {
                const int li = p * 256 + tid;
                const int m = li >> 3, k4 = li & 7;
                const float4 v = *reinterpret_cast<const float4*>(
                    &z[(size_t)(m0 + m) * DIM + k0 + k4 * 4]);
                ushort h[4], mm[4], ll[4];
                bsplit3(v.x, h[0], mm[0], ll[0]);
                bsplit3(v.y, h[1], mm[1], ll[1]);
                bsplit3(v.z, h[2], mm[2], ll[2]);
                bsplit3(v.w, h[3], mm[3], ll[3]);
                const int g = m >> 4, gr = (k4 >> 1) * 16 + (m & 15), j0 = (k4 & 1) * 4;
                *reinterpret_cast<ushort4*>(&A_lds[0][g][gr][j0]) = make_ushort4(h[0], h[1], h[2], h[3]);
                *reinterpret_cast<ushort4*>(&A_lds[1][g][gr][j0]) = make_ushort4(mm[0], mm[1], mm[2], mm[3]);
                *reinterpret_cast<ushort4*>(&A_lds[2][g][gr][j0]) = make_ushort4(ll[0], ll[1], ll[2], ll[3]);
            }
            __syncthreads();
            bf16x8 bfr[3][4];
#pragma unroll
            for (int t = 0; t < 3; t++)
#pragma unroll
                for (int in = 0; in < 4; in++)
                    bfr[t][in] = *reinterpret_cast<const bf16x8*>(&B_lds[t][(wn >> 4) + in][lane][0]);
#pragma unroll
            for (int t = 0; t < 3; t++) {
                bf16x8 afr[4];
#pragma unroll
                for (int im = 0; im < 4; im++)
                    afr[im] = *reinterpret_cast<const bf16x8*>(&A_lds[t][(wm >> 4) + im][lane][0]);
#pragma unroll
                for (int u = 0; u < 3 - t; u++)
#pragma unroll
                    for (int im = 0; im < 4; im++)
#pragma unroll
                        for (int in = 0; in < 4; in++)
                            acc[im][in] = __builtin_amdgcn_mfma_f32_16x16x32_bf16(
                                afr[im], bfr[u][in], acc[im][in], 0, 0, 0);
            }
            __syncthreads();
        }
#pragma unroll
        for (int im = 0; im < 4; im++)
#pragma unroll
            for (int r = 0; r < 4; r++) {
                const int s = im * 4 + r;
#pragma unroll
                for (int in = 0; in < 4; in++) {
                    const float dv = fmaf(-2.f, acc[im][in][r], zn[s]);
                    const int code = n0 + wn + in * 16 + lane16;
                    if (dv < bestv[s]) { bestv[s] = dv; besti[s] = code; }
                }
            }
    }
#pragma unroll
    for (int s = 0; s < 16; s++) {
        float bv = bestv[s];
        int bi = besti[s];
#pragma unroll
        for (int off = 1; off < 16; off <<= 1) {
            const float v2 = __shfl_xor(bv, off, 64);
            const int i2 = __shfl_xor(bi, off, 64);
            if (v2 < bv || (v2 == bv && i2 < bi)) { bv = v2; bi = i2; }
        }
        if (lane16 == 0) {
            const int im = s >> 2, r = s & 3;
            const int rloc = im * 16 + lq * 4 + r;
            mvals[w >> 1][w & 1][rloc] = bv;
            midxs[w >> 1][w & 1][rloc] = bi;
        }
    }
    __syncthreads();
    if (tid < 128) {
        const int wp = tid >> 6, rl = tid & 63;
        const float v0 = mvals[wp][0][rl], v1 = mvals[wp][1][rl];
        const int i0 = midxs[wp][0][rl], i1 = midxs[wp][1][rl];
        float bv; int bi;
        if (v1 < v0 || (v1 == v0 && i1 < i0)) { bv = v1; bi = i1; }
        else { bv = v0; bi = i0; }
        const int row = m0 + wp * 64 + rl;
        cand_val[(size_t)q * N_ROWS + row] = bv;
        cand_idx[(size_t)q * N_ROWS + row] = bi;
    }
}

// ---------------- fallback fp32 vector argmin (R2, proven) ----------------
#define MT 64
#define ET 128
#define KT 16
__launch_bounds__(256, 2)
__global__ void argmin_vec_kernel(const float* __restrict__ z, const float* __restrict__ emb,
                                  const float* __restrict__ znorm,
                                  float* __restrict__ cand_val, int* __restrict__ cand_idx) {
    __shared__ float As[KT][68];
    __shared__ float Bs[KT][132];
    __shared__ float rv[MT][17];
    __shared__ int ri[MT][17];
    const int tid = threadIdx.x;
    const int tx = tid & 15;
    const int ty = tid >> 4;
    const int m0 = blockIdx.x * MT;
    const int ebase = blockIdx.y * (NE / 2);
    float zn[4];
#pragma unroll
    for (int r = 0; r < 4; r++) zn[r] = znorm[m0 + ty * 4 + r];
    float bestv[4]; int besti[4];
#pragma unroll
    for (int r = 0; r < 4; r++) { bestv[r] = INFINITY; besti[r] = 0; }
    const int k4 = tid & 3;
    const int ldrow = tid >> 2;
    for (int et = 0; et < (NE / 2) / ET; ++et) {
        const int e0 = ebase + et * ET;
        float acc[4][8];
#pragma unroll
        for (int r = 0; r < 4; r++)
#pragma unroll
            for (int c = 0; c < 8; c++) acc[r][c] = 0.f;
        for (int kt = 0; kt < DIM / KT; ++kt) {
            {
                const float4 v = *reinterpret_cast<const float4*>(
                    &z[(size_t)(m0 + ldrow) * DIM + kt * KT + k4 * 4]);
                As[k4 * 4 + 0][ldrow] = v.x; As[k4 * 4 + 1][ldrow] = v.y;
                As[k4 * 4 + 2][ldrow] = v.z; As[k4 * 4 + 3][ldrow] = v.w;
            }
#pragma unroll
            for (int i = 0; i < 2; i++) {
                const int code = ldrow + i * 64;
                const float4 v = *reinterpret_cast<const float4*>(
                    &emb[(size_t)(e0 + code) * DIM + kt * KT + k4 * 4]);
                Bs[k4 * 4 + 0][code] = v.x; Bs[k4 * 4 + 1][code] = v.y;
                Bs[k4 * 4 + 2][code] = v.z; Bs[k4 * 4 + 3][code] = v.w;
            }
            __syncthreads();
#pragma unroll
            for (int kk = 0; kk < KT; kk++) {
                const float4 a = *reinterpret_cast<const float4*>(&As[kk][ty * 4]);
                const float4 b0 = *reinterpret_cast<const float4*>(&Bs[kk][tx * 4]);
                const float4 b1 = *reinterpret_cast<const float4*>(&Bs[kk][64 + tx * 4]);
                const float av[4] = {a.x, a.y, a.z, a.w};
                const float bv[8] = {b0.x, b0.y, b0.z, b0.w, b1.x, b1.y, b1.z, b1.w};
#pragma unroll
                for (int r = 0; r < 4; r++)
#pragma unroll
                    for (int c = 0; c < 8; c++)
                        acc[r][c] = fmaf(av[r], bv[c], acc[r][c]);
            }
            __syncthreads();
        }
#pragma unroll
        for (int c = 0; c < 8; c++) {
            const int lc = (c < 4) ? (tx * 4 + c) : (64 + tx * 4 + (c - 4));
            const int gidx = e0 + lc;
#pragma unroll
            for (int r = 0; r < 4; r++) {
                const float t = fmaf(-2.f, acc[r][c], zn[r]);
                if (t < bestv[r]) { bestv[r] = t; besti[r] = gidx; }
            }
        }
    }
#pragma unroll
    for (int r = 0; r < 4; r++) { rv[ty * 4 + r][tx] = bestv[r]; ri[ty * 4 + r][tx] = besti[r]; }
    __syncthreads();
    if (tid < MT) {
        float bv = rv[tid][0]; int bi = ri[tid][0];
#pragma unroll
        for (int t = 1; t < 16; t++) {
            const float v = rv[tid][t]; const int i = ri[tid][t];
            if (v < bv || (v == bv && i < bi)) { bv = v; bi = i; }
        }
        cand_val[(size_t)blockIdx.y * N_ROWS + m0 + tid] = bv;
        cand_idx[(size_t)blockIdx.y * N_ROWS + m0 + tid] = bi;
    }
}

// ---------------- finalize: pick idx over nq candidates, gather, loss ----
__global__ void finalize_kernel(const float* __restrict__ z, const float* __restrict__ emb,
                                const float* __restrict__ cand_val, const int* __restrict__ cand_idx,
                                int nq, float* __restrict__ out, int* __restrict__ hist,
                                float* __restrict__ lossbuf) {
    __shared__ float sdata[256];
    const int n = blockIdx.x;
    float v = cand_val[n];
    int idx = cand_idx[n];
    for (int qq = 1; qq < nq; qq++) {
        const float vq = cand_val[(size_t)qq * N_ROWS + n];
        const int iq = cand_idx[(size_t)qq * N_ROWS + n];
        if (vq < v || (vq == v && iq < idx)) { v = vq; idx = iq; }
    }
    const float* e = emb + (size_t)idx * DIM;
    const float* zr = z + (size_t)n * DIM;
    const int tid = threadIdx.x;
    float ls = 0.f;
#pragma unroll
    for (int j = 0; j < 2; j++) {
        const int k = tid + j * 256;
        const float zq = e[k];
        const float zv = zr[k];
        const float d = zq - zv;
        out[ZQ_OFF + (size_t)n * DIM + k] = zv + d;  // match ref rounding: z + (z_q - z)
        ls += d * d;
    }
    sdata[tid] = ls;
    __syncthreads();
    for (int s = 128; s; s >>= 1) {
        if (tid < s) sdata[tid] += sdata[tid + s];
        __syncthreads();
    }
    if (tid == 0) {
        atomicAdd(lossbuf + (n & 255), sdata[0]);
        atomicAdd(hist + idx, 1);
        out[ME_OFF + (size_t)n * NE + idx] = 1.0f;
        out[IDX_OFF + n] = (float)idx;
    }
}

// ---------------- perplexity + final loss ----------------
__global__ void perp_kernel(const int* __restrict__ hist, const float* __restrict__ lossbuf,
                            float* __restrict__ out) {
    __shared__ float sdata[256];
    const int tid = threadIdx.x;
    float s = 0.f;
    for (int b = tid; b < NE; b += 256) {
        const float p = (float)hist[b] * (1.0f / 16384.f);
        s += p * logf(p + 1e-10f);
    }
    sdata[tid] = s;
    __syncthreads();
    for (int st = 128; st; st >>= 1) {
        if (tid < st) sdata[tid] += sdata[tid + st];
        __syncthreads();
    }
    if (tid == 0) out[PERP_OFF] = expf(-sdata[0]);
    __syncthreads();
    sdata[tid] = lossbuf[tid];
    __syncthreads();
    for (int st = 128; st; st >>= 1) {
        if (tid < st) sdata[tid] += sdata[tid + st];
        __syncthreads();
    }
    if (tid == 0) out[LOSS_OFF] = sdata[0] * (1.25f / 8388608.f);
}

extern "C" void kernel_launch(void* const* d_in, const int* in_sizes, int n_in,
                              void* d_out, int out_size, void* d_ws, size_t ws_size,
                              hipStream_t stream) {
    const float* z = (const float*)d_in[0];    // [32,512,512]
    const float* emb = (const float*)d_in[1];  // [8192,512]
    float* out = (float*)d_out;
    unsigned char* w = (unsigned char*)d_ws;

    const size_t ZSP = 16777216UL;  // one z split term (16384*512*2 B)
    const size_t ESP = 8388608UL;   // one emb split term (8192*512*2 B)

    // big-path layout (3-term splits for both operands)
    const size_t OB_Z = 0;
    const size_t OB_E = 3 * ZSP;
    const size_t OB_ZN = OB_E + 3 * ESP;
    const size_t OB_CV = OB_ZN + 65536;
    const size_t OB_CI = OB_CV + 262144;
    const size_t OB_H = OB_CI + 262144;
    const size_t OB_LB = OB_H + 32768;
    const size_t NEED_BIG = OB_LB + 1024;
    // mid-path layout (avoid libc macro names like M_E)
    const size_t OM_E = 0;
    const size_t OM_ZN = 3 * ESP;
    const size_t OM_CV = OM_ZN + 65536;
    const size_t OM_CI = OM_CV + 262144;
    const size_t OM_H = OM_CI + 262144;
    const size_t OM_LB = OM_H + 32768;
    const size_t NEED_MID = OM_LB + 1024;

    if (ws_size >= NEED_BIG) {
        ushort* zh = (ushort*)(w + OB_Z);
        ushort* zm = (ushort*)(w + OB_Z + ZSP);
        ushort* zl = (ushort*)(w + OB_Z + 2 * ZSP);
        ushort* eh = (ushort*)(w + OB_E);
        ushort* em = (ushort*)(w + OB_E + ESP);
        ushort* el = (ushort*)(w + OB_E + 2 * ESP);
        float* znorm = (float*)(w + OB_ZN);
        float* cand_val = (float*)(w + OB_CV);
        int* cand_idx = (int*)(w + OB_CI);
        int* hist = (int*)(w + OB_H);
        float* lossbuf = (float*)(w + OB_LB);

        (void)hipMemsetAsync(hist, 0, 32768, stream);
        (void)hipMemsetAsync(lossbuf, 0, 1024, stream);
        hipLaunchKernelGGL(split3g_kernel, dim3(N_ROWS * 64 / 256), dim3(256), 0, stream,
                           z, zh, zm, zl, znorm, N_ROWS);
        hipLaunchKernelGGL(split3g_kernel, dim3(NE * 64 / 256), dim3(256), 0, stream,
                           emb, eh, em, el, (float*)nullptr, NE);
        hipLaunchKernelGGL(argmin_mfma2z_kernel, dim3(N_ROWS / MBLK, 4), dim3(256), 0, stream,
                           zh, zm, zl, eh, em, el, znorm, out, cand_val, cand_idx);
        hipLaunchKernelGGL(finalize_kernel, dim3(N_ROWS), dim3(256), 0, stream,
                           z, emb, cand_val, cand_idx, 4, out, hist, lossbuf);
        hipLaunchKernelGGL(perp_kernel, dim3(1), dim3(256), 0, stream, hist, lossbuf, out);
    } else if (ws_size >= NEED_MID) {
        ushort* eh = (ushort*)(w + OM_E);
        ushort* em = (ushort*)(w + OM_E + ESP);
        ushort* el = (ushort*)(w + OM_E + 2 * ESP);
        float* znorm = (float*)(w + OM_ZN);
        float* cand_val = (float*)(w + OM_CV);
        int* cand_idx = (int*)(w + OM_CI);
        int* hist = (int*)(w + OM_H);
        float* lossbuf = (float*)(w + OM_LB);

        (void)hipMemsetAsync((void*)(out + ME_OFF), 0, 134217728UL * 4, stream);
        (void)hipMemsetAsync(hist, 0, 32768, stream);
        (void)hipMemsetAsync(lossbuf, 0, 1024, stream);
        hipLaunchKernelGGL(emb_split_kernel, dim3(4096), dim3(256), 0, stream, emb, eh, em, el);
        hipLaunchKernelGGL(znorm_kernel, dim3(4096), dim3(256), 0, stream, z, znorm);
        hipLaunchKernelGGL(argmin_mfma_kernel, dim3(N_ROWS / MBLK, 4), dim3(256), 0, stream,
                           z, eh, em, el, znorm, cand_val, cand_idx);
        hipLaunchKernelGGL(finalize_kernel, dim3(N_ROWS), dim3(256), 0, stream,
                           z, emb, cand_val, cand_idx, 4, out, hist, lossbuf);
        hipLaunchKernelGGL(perp_kernel, dim3(1), dim3(256), 0, stream, hist, lossbuf, out);
    } else {
        float* znorm = (float*)w;
        float* cand_val = (float*)(w + 65536);
        int* cand_idx = (int*)(w + 65536 + 131072);
        int* hist = (int*)(w + 65536 + 262144);
        float* lossbuf = (float*)(w + 65536 + 262144 + 32768);

        (void)hipMemsetAsync((void*)(out + ME_OFF), 0, 134217728UL * 4, stream);
        (void)hipMemsetAsync(hist, 0, 32768, stream);
        (void)hipMemsetAsync(lossbuf, 0, 1024, stream);
        hipLaunchKernelGGL(znorm_kernel, dim3(4096), dim3(256), 0, stream, z, znorm);
        hipLaunchKernelGGL(argmin_vec_kernel, dim3(N_ROWS / MT, 2), dim3(256), 0, stream,
                           z, emb, znorm, cand_val, cand_idx);
        hipLaunchKernelGGL(finalize_kernel, dim3(N_ROWS), dim3(256), 0, stream,
                           z, emb, cand_val, cand_idx, 2, out, hist, lossbuf);
        hipLaunchKernelGGL(perp_kernel, dim3(1), dim3(256), 0, stream, hist, lossbuf, out);
    }
}